// Round 12
// baseline (143.099 us; speedup 1.0000x reference)
//
#include <hip/hip_runtime.h>

typedef unsigned int u32;
typedef unsigned short u16;
typedef __attribute__((ext_vector_type(8))) short short8;
typedef __attribute__((ext_vector_type(4))) float f32x4;

static constexpr int NN = 50000;
static constexpr int NE = 800000;
static constexpr int HH = 128;
static constexpr int NB1 = (NN + 1023) / 1024;   // Tier B scan blocks
static constexpr int NBK = 196;                   // buckets of 256 nodes
static constexpr int EPB = 8192;                  // edges per hist/scatter block
static constexpr int NEB = (NE + EPB - 1) / EPB;  // 98 edge blocks

// ---- bf16 helpers (RNE) ----
__device__ __forceinline__ u32 bf16r(float f) {
  u32 u = __builtin_bit_cast(u32, f);
  return (u + 0x7FFFu + ((u >> 16) & 1u)) >> 16;
}
__device__ __forceinline__ u32 pk2(float lo, float hi) { return bf16r(lo) | (bf16r(hi) << 16); }
__device__ __forceinline__ float bl(u32 p) { return __builtin_bit_cast(float, p << 16); }
__device__ __forceinline__ float bh(u32 p) { return __builtin_bit_cast(float, p & 0xFFFF0000u); }

// ================= prep + ph1 bucket histogram =================
// blocks [0,3125): cvt_x ; [3125,3189): w1t ; [3189,3253): w2t ;
// 3253: zero stats ; [3254, 3254+NEB): per-edge-block bucket histogram
__global__ __launch_bounds__(256) void prep_kernel(const float4* __restrict__ x,
                                                   uint4* __restrict__ x16,
                                                   const float* __restrict__ W1,
                                                   u16* __restrict__ w1t,
                                                   const float* __restrict__ W2,
                                                   u16* __restrict__ w2t,
                                                   float* __restrict__ stats,
                                                   const int* __restrict__ ei,
                                                   int* __restrict__ hist2d) {
  __shared__ int hist[NBK];
  const int b = blockIdx.x, t = threadIdx.x;
  if (b < 3125) {
    const int i = b * 256 + t;  // < 800000 = NN*HH/8
    const float4 a = x[2 * i];
    const float4 c = x[2 * i + 1];
    uint4 o;
    o.x = pk2(a.x, a.y);
    o.y = pk2(a.z, a.w);
    o.z = pk2(c.x, c.y);
    o.w = pk2(c.z, c.w);
    x16[i] = o;
  } else if (b < 3189) {
    const int o = (b - 3125) * 256 + t;  // < 16384
    const int n = o >> 7, k = o & 127;
    w1t[o] = (u16)bf16r(W1[k * 128 + n]);
  } else if (b < 3253) {
    const int o = (b - 3189) * 256 + t;
    const int n = o >> 7, k = o & 127;
    w2t[o] = (u16)bf16r(W2[k * 128 + n]);
  } else if (b == 3253) {
    stats[t] = 0.f;
  } else {
    const int hb = b - 3254;  // [0, NEB)
    for (int i = t; i < NBK; i += 256) hist[i] = 0;
    __syncthreads();
    const int e0 = hb * EPB;
    const int e1 = min(e0 + EPB, NE);
    for (int e = e0 + t; e < e1; e += 256) atomicAdd(&hist[ei[NE + e] >> 8], 1);
    __syncthreads();
    for (int i = t; i < NBK; i += 256) hist2d[hb * NBK + i] = hist[i];
  }
}

// ================= ph3: scatter edges -> bucket-contiguous packed array ======
// Each block derives its own per-bucket write bases from hist2d.
__global__ __launch_bounds__(256) void ph3_kernel(const int* __restrict__ ei,
                                                  const int* __restrict__ hist2d,
                                                  u32* __restrict__ packed) {
  __shared__ int cur[NBK];
  __shared__ int tot[256];
  const int b = blockIdx.x, t = threadIdx.x;
  int total = 0, partial = 0;
  if (t < NBK) {
    for (int bb = 0; bb < NEB; ++bb) {
      const int v = hist2d[bb * NBK + t];
      total += v;
      if (bb < b) partial += v;
    }
  }
  tot[t] = total;
  __syncthreads();
  for (int off = 1; off < 256; off <<= 1) {
    const int add = (t >= off) ? tot[t - off] : 0;
    __syncthreads();
    tot[t] += add;
    __syncthreads();
  }
  if (t < NBK) cur[t] = (t ? tot[t - 1] : 0) + partial;
  __syncthreads();
  const int e0 = b * EPB;
  const int e1 = min(e0 + EPB, NE);
  for (int e = e0 + t; e < e1; e += 256) {
    const int s = ei[e];
    const int d = ei[NE + e];
    const int pos = atomicAdd(&cur[d >> 8], 1);
    packed[pos] = (u32)s | ((u32)(d & 255) << 16);
  }
}

// ================= ph4: per-bucket counting sort -> srcl + offs ==============
// Each block derives bucket bases from hist2d itself.
__global__ __launch_bounds__(256) void ph4_kernel(const int* __restrict__ hist2d,
                                                  const u32* __restrict__ packed,
                                                  int* __restrict__ offs,
                                                  int* __restrict__ srcl) {
  __shared__ int hist[256];
  __shared__ int scn[256];
  __shared__ int sb[2];
  const int b = blockIdx.x, t = threadIdx.x;
  int total = 0;
  if (t < NBK)
    for (int bb = 0; bb < NEB; ++bb) total += hist2d[bb * NBK + t];
  scn[t] = total;
  __syncthreads();
  for (int off = 1; off < 256; off <<= 1) {
    const int add = (t >= off) ? scn[t - off] : 0;
    __syncthreads();
    scn[t] += add;
    __syncthreads();
  }
  if (t == b) {
    sb[0] = b ? scn[b - 1] : 0;
    sb[1] = scn[b];
  }
  __syncthreads();
  const int base = sb[0];
  const int cnt = sb[1] - base;

  hist[t] = 0;
  __syncthreads();
  for (int i = t; i < cnt; i += 256) atomicAdd(&hist[packed[base + i] >> 16], 1);
  __syncthreads();
  scn[t] = hist[t];
  __syncthreads();
  for (int off = 1; off < 256; off <<= 1) {
    const int add = (t >= off) ? scn[t - off] : 0;
    __syncthreads();
    scn[t] += add;
    __syncthreads();
  }
  const int excl = t ? scn[t - 1] : 0;
  const int node = b * 256 + t;
  if (node < NN) offs[node] = base + excl;
  if (b == NBK - 1 && t == 0) offs[NN] = NE;
  __syncthreads();
  hist[t] = excl;  // reuse as cursor
  __syncthreads();
  for (int i = t; i < cnt; i += 256) {
    const u32 p = packed[base + i];
    const int r = atomicAdd(&hist[p >> 16], 1);
    srcl[base + r] = (int)(p & 0xFFFFu);
  }
}

// ================= gather (bf16, half-wave per node, 16-deep MLP) ============
__global__ __launch_bounds__(256) void gather16_kernel(const u32* __restrict__ x16,
                                                       const int* __restrict__ offs,
                                                       const int* __restrict__ srcl,
                                                       u32* __restrict__ h0) {
  const int hw = (blockIdx.x * 256 + threadIdx.x) >> 5;  // half-wave id
  const int l31 = threadIdx.x & 31;
  const int nhw = gridDim.x * 8;
  for (int node = hw; node < NN; node += nhw) {
    const uint2 sv = reinterpret_cast<const uint2*>(x16 + (size_t)node * 64)[l31];
    float a0 = bl(sv.x), a1 = bh(sv.x), a2 = bl(sv.y), a3 = bh(sv.y);
    const int beg = offs[node], end = offs[node + 1];
    int e = beg;
    for (; e + 16 <= end; e += 16) {
      int s[16];
#pragma unroll
      for (int j = 0; j < 16; ++j) s[j] = srcl[e + j];
      uint2 v[16];
#pragma unroll
      for (int j = 0; j < 16; ++j)
        v[j] = reinterpret_cast<const uint2*>(x16 + (size_t)s[j] * 64)[l31];
#pragma unroll
      for (int j = 0; j < 16; ++j) {
        a0 += bl(v[j].x); a1 += bh(v[j].x);
        a2 += bl(v[j].y); a3 += bh(v[j].y);
      }
    }
    for (; e + 8 <= end; e += 8) {
      int s[8];
#pragma unroll
      for (int j = 0; j < 8; ++j) s[j] = srcl[e + j];
      uint2 v[8];
#pragma unroll
      for (int j = 0; j < 8; ++j)
        v[j] = reinterpret_cast<const uint2*>(x16 + (size_t)s[j] * 64)[l31];
#pragma unroll
      for (int j = 0; j < 8; ++j) {
        a0 += bl(v[j].x); a1 += bh(v[j].x);
        a2 += bl(v[j].y); a3 += bh(v[j].y);
      }
    }
    for (; e < end; ++e) {
      const uint2 v = reinterpret_cast<const uint2*>(x16 + (size_t)srcl[e] * 64)[l31];
      a0 += bl(v.x); a1 += bh(v.x);
      a2 += bl(v.y); a3 += bh(v.y);
    }
    uint2 o;
    o.x = pk2(a0, a1);
    o.y = pk2(a2, a3);
    reinterpret_cast<uint2*>(h0 + (size_t)node * 64)[l31] = o;
  }
}

// ---------------- fused 2-layer MLP (MFMA) + column stats --------------------
__global__ __launch_bounds__(256) void fused_mlp_kernel(const u16* __restrict__ h0,
                                                        const u16* __restrict__ w1t,
                                                        const float* __restrict__ b1,
                                                        const u16* __restrict__ w2t,
                                                        const float* __restrict__ b2,
                                                        u32* __restrict__ h2,
                                                        float* __restrict__ stats,
                                                        int nchunk) {
  __shared__ __align__(16) u16 hs[16][136];  // padded: 272B row stride
  __shared__ float sstats[256];
  const int t = threadIdx.x;
  const int w = t >> 6;
  const int lane = t & 63;
  const int lhi = lane >> 4, llo = lane & 15;
  sstats[t] = 0.f;

  short8 w1f[2][4], w2f[2][4];
  float4 bs1[2], bs2[2];
#pragma unroll
  for (int c = 0; c < 2; ++c) {
    const int ct = 2 * w + c;
#pragma unroll
    for (int kb = 0; kb < 4; ++kb) {
      w1f[c][kb] = *reinterpret_cast<const short8*>(w1t + (size_t)(16 * ct + llo) * 128 + kb * 32 + lhi * 8);
      w2f[c][kb] = *reinterpret_cast<const short8*>(w2t + (size_t)(16 * ct + llo) * 128 + kb * 32 + lhi * 8);
    }
    bs1[c] = *reinterpret_cast<const float4*>(b1 + ct * 16 + lhi * 4);
    bs2[c] = *reinterpret_cast<const float4*>(b2 + ct * 16 + lhi * 4);
  }
  __syncthreads();  // sstats init visible to all

  for (int ch = blockIdx.x; ch < nchunk; ch += gridDim.x) {
    const int row0 = ch * 16;

    // ---- layer 1: A from global ----
    const u16* arow = h0 + (size_t)(row0 + llo) * 128;
    short8 afr[4];
#pragma unroll
    for (int kb = 0; kb < 4; ++kb)
      afr[kb] = *reinterpret_cast<const short8*>(arow + kb * 32 + lhi * 8);

    f32x4 acc0 = {0.f, 0.f, 0.f, 0.f};
    f32x4 acc1 = {0.f, 0.f, 0.f, 0.f};
#pragma unroll
    for (int kb = 0; kb < 4; ++kb) {
      acc0 = __builtin_amdgcn_mfma_f32_16x16x32_bf16(w1f[0][kb], afr[kb], acc0, 0, 0, 0);
      acc1 = __builtin_amdgcn_mfma_f32_16x16x32_bf16(w1f[1][kb], afr[kb], acc1, 0, 0, 0);
    }

    // ---- ReLU + pack to LDS ----
#pragma unroll
    for (int c = 0; c < 2; ++c) {
      const int ct = 2 * w + c;
      const f32x4 a = c ? acc1 : acc0;
      const float4 bb = c ? bs1[1] : bs1[0];
      const float v0 = fmaxf(a[0] + bb.x, 0.f);
      const float v1 = fmaxf(a[1] + bb.y, 0.f);
      const float v2 = fmaxf(a[2] + bb.z, 0.f);
      const float v3 = fmaxf(a[3] + bb.w, 0.f);
      u32* dst = reinterpret_cast<u32*>(&hs[llo][ct * 16 + lhi * 4]);
      dst[0] = pk2(v0, v1);
      dst[1] = pk2(v2, v3);
    }
    __syncthreads();

    // ---- layer 2: A from LDS ----
    short8 af2[4];
#pragma unroll
    for (int kb = 0; kb < 4; ++kb)
      af2[kb] = *reinterpret_cast<const short8*>(&hs[llo][kb * 32 + lhi * 8]);

    f32x4 dcc0 = {0.f, 0.f, 0.f, 0.f};
    f32x4 dcc1 = {0.f, 0.f, 0.f, 0.f};
#pragma unroll
    for (int kb = 0; kb < 4; ++kb) {
      dcc0 = __builtin_amdgcn_mfma_f32_16x16x32_bf16(w2f[0][kb], af2[kb], dcc0, 0, 0, 0);
      dcc1 = __builtin_amdgcn_mfma_f32_16x16x32_bf16(w2f[1][kb], af2[kb], dcc1, 0, 0, 0);
    }
    __syncthreads();  // protect hs before next chunk's writes

    // ---- epilogue: bias, bf16 store, fused column stats ----
#pragma unroll
    for (int c = 0; c < 2; ++c) {
      const int ct = 2 * w + c;
      const f32x4 a = c ? dcc1 : dcc0;
      const float4 bb = c ? bs2[1] : bs2[0];
      float v0 = a[0] + bb.x;
      float v1 = a[1] + bb.y;
      float v2 = a[2] + bb.z;
      float v3 = a[3] + bb.w;
      u32* op = h2 + (size_t)(row0 + llo) * 64 + ct * 8 + lhi * 2;
      op[0] = pk2(v0, v1);
      op[1] = pk2(v2, v3);
      float q0 = v0 * v0, q1 = v1 * v1, q2 = v2 * v2, q3 = v3 * v3;
#pragma unroll
      for (int m = 1; m < 16; m <<= 1) {
        v0 += __shfl_xor(v0, m, 64); v1 += __shfl_xor(v1, m, 64);
        v2 += __shfl_xor(v2, m, 64); v3 += __shfl_xor(v3, m, 64);
        q0 += __shfl_xor(q0, m, 64); q1 += __shfl_xor(q1, m, 64);
        q2 += __shfl_xor(q2, m, 64); q3 += __shfl_xor(q3, m, 64);
      }
      if (llo == 0) {
        const int cb = ct * 16 + lhi * 4;
        atomicAdd(&sstats[cb + 0], v0); atomicAdd(&sstats[cb + 1], v1);
        atomicAdd(&sstats[cb + 2], v2); atomicAdd(&sstats[cb + 3], v3);
        atomicAdd(&sstats[128 + cb + 0], q0); atomicAdd(&sstats[128 + cb + 1], q1);
        atomicAdd(&sstats[128 + cb + 2], q2); atomicAdd(&sstats[128 + cb + 3], q3);
      }
    }
  }
  __syncthreads();
  atomicAdd(&stats[t], sstats[t]);
}

// ---------------- batchnorm: h2 bf16 -> out fp32 ----------------
__global__ __launch_bounds__(256) void bn16_kernel(const u32* __restrict__ h2,
                                                   const float* __restrict__ stats,
                                                   const float* __restrict__ gamma,
                                                   const float* __restrict__ beta,
                                                   float* __restrict__ out, float invn) {
  __shared__ float scale_s[128], shift_s[128];
  const int t = threadIdx.x;
  if (t < 128) {
    const float mean = stats[t] * invn;
    float var = fmaf(-mean, mean, stats[128 + t] * invn);
    var = fmaxf(var, 0.f);
    const float rs = rsqrtf(var + 1e-5f);
    const float sc = gamma[t] * rs;
    scale_s[t] = sc;
    shift_s[t] = fmaf(-mean, sc, beta[t]);
  }
  __syncthreads();
  int i = blockIdx.x * 256 + t;
  const int stride = gridDim.x * 256;
  for (; i < NN * 64; i += stride) {
    const int c = (i & 63) * 2;
    const u32 p = h2[i];
    float2 o;
    o.x = fmaf(bl(p), scale_s[c + 0], shift_s[c + 0]);
    o.y = fmaf(bh(p), scale_s[c + 1], shift_s[c + 1]);
    *reinterpret_cast<float2*>(out + 2 * (size_t)i) = o;
  }
}

// ================= Tier B/C fallback kernels (fp32) =================
__global__ void zero_stats_kernel(float* __restrict__ stats) { stats[threadIdx.x] = 0.f; }

__global__ __launch_bounds__(256) void zero_int_kernel(int* __restrict__ p, int n) {
  int i = blockIdx.x * blockDim.x + threadIdx.x;
  const int stride = gridDim.x * blockDim.x;
  for (; i < n; i += stride) p[i] = 0;
}

__global__ __launch_bounds__(256) void count_kernel(const int* __restrict__ ei,
                                                    int* __restrict__ cnt) {
  const int e = blockIdx.x * blockDim.x + threadIdx.x;
  if (e < NE) atomicAdd(&cnt[ei[NE + e]], 1);
}

__global__ __launch_bounds__(256) void scan1_kernel(const int* __restrict__ cnt,
                                                    int* __restrict__ offs,
                                                    int* __restrict__ partials) {
  __shared__ int tsum[256];
  const int b = blockIdx.x, t = threadIdx.x;
  const int base = b * 1024 + t * 4;
  int v[4];
  int s = 0;
#pragma unroll
  for (int j = 0; j < 4; ++j) {
    const int idx = base + j;
    v[j] = (idx < NN) ? cnt[idx] : 0;
    s += v[j];
  }
  tsum[t] = s;
  __syncthreads();
#pragma unroll
  for (int off = 1; off < 256; off <<= 1) {
    const int add = (t >= off) ? tsum[t - off] : 0;
    __syncthreads();
    tsum[t] += add;
    __syncthreads();
  }
  int excl = (t ? tsum[t - 1] : 0);
#pragma unroll
  for (int j = 0; j < 4; ++j) {
    const int idx = base + j;
    if (idx < NN) offs[idx] = excl;
    excl += v[j];
  }
  if (t == 255) partials[b] = tsum[255];
}

__global__ void scan2_kernel(int* __restrict__ partials, int nb) {
  const int t = threadIdx.x;
  int v = (t < nb) ? partials[t] : 0;
#pragma unroll
  for (int off = 1; off < 64; off <<= 1) {
    const int n = __shfl_up(v, off, 64);
    if (t >= off) v += n;
  }
  int excl = __shfl_up(v, 1, 64);
  if (t == 0) excl = 0;
  if (t < nb) partials[t] = excl;
}

__global__ __launch_bounds__(256) void scan3_kernel(int* __restrict__ offs,
                                                    int* __restrict__ cursor,
                                                    const int* __restrict__ partials) {
  const int b = blockIdx.x;
  const int add = partials[b];
#pragma unroll
  for (int j = 0; j < 4; ++j) {
    const int idx = b * 1024 + threadIdx.x + j * 256;
    if (idx < NN) {
      const int o = offs[idx] + add;
      offs[idx] = o;
      cursor[idx] = o;
    }
  }
  if (b == 0 && threadIdx.x == 0) offs[NN] = NE;
}

__global__ __launch_bounds__(256) void fill_kernel(const int* __restrict__ ei,
                                                   int* __restrict__ cursor,
                                                   int* __restrict__ srcl) {
  const int e = blockIdx.x * blockDim.x + threadIdx.x;
  if (e >= NE) return;
  const int s = ei[e];
  const int d = ei[NE + e];
  const int pos = atomicAdd(&cursor[d], 1);
  srcl[pos] = s;
}

__global__ __launch_bounds__(256) void gather_kernel(const float* __restrict__ x,
                                                     const int* __restrict__ offs,
                                                     const int* __restrict__ srcl,
                                                     float* __restrict__ out) {
  const int wave = (blockIdx.x * 256 + threadIdx.x) >> 6;
  const int lane = threadIdx.x & 63;
  const int nwaves = gridDim.x * 4;
  for (int node = wave; node < NN; node += nwaves) {
    float2 acc = *reinterpret_cast<const float2*>(x + (size_t)node * HH + lane * 2);
    const int beg = offs[node], end = offs[node + 1];
    for (int e = beg; e < end; ++e) {
      const int s = srcl[e];
      const float2 v = *reinterpret_cast<const float2*>(x + (size_t)s * HH + lane * 2);
      acc.x += v.x;
      acc.y += v.y;
    }
    *reinterpret_cast<float2*>(out + (size_t)node * HH + lane * 2) = acc;
  }
}

__global__ __launch_bounds__(256) void copy_x_kernel(const float4* __restrict__ x,
                                                     float4* __restrict__ h, int n4) {
  int i = blockIdx.x * blockDim.x + threadIdx.x;
  const int stride = gridDim.x * blockDim.x;
  for (; i < n4; i += stride) h[i] = x[i];
}

__global__ __launch_bounds__(256) void scatter_kernel(const float* __restrict__ x,
                                                      const int* __restrict__ ei,
                                                      float* __restrict__ h) {
  const long long tid = (long long)blockIdx.x * blockDim.x + threadIdx.x;
  const int e = (int)(tid >> 5);
  if (e >= NE) return;
  const int c = (int)(tid & 31);
  const int s = ei[e];
  const int d = ei[NE + e];
  const float4 v = *reinterpret_cast<const float4*>(x + (size_t)s * HH + c * 4);
  float* dp = h + (size_t)d * HH + c * 4;
  atomicAdd(dp + 0, v.x);
  atomicAdd(dp + 1, v.y);
  atomicAdd(dp + 2, v.z);
  atomicAdd(dp + 3, v.w);
}

template <bool RELU>
__global__ __launch_bounds__(256, 2) void gemm128_kernel(const float* in,
                                                         const float* __restrict__ W,
                                                         const float* __restrict__ bias,
                                                         float* out,
                                                         int nrows, int nchunks) {
  __shared__ float Ws[128][128];
  __shared__ float rows_s[32][128];
  const int t = threadIdx.x;
  for (int i = t; i < 128 * 128 / 4; i += 256) {
    reinterpret_cast<float4*>(&Ws[0][0])[i] = reinterpret_cast<const float4*>(W)[i];
  }
  const int col4 = (t & 31) * 4;
  const int rowg = (t >> 5) * 4;
  const float4 b4 = *reinterpret_cast<const float4*>(bias + col4);

  for (int chunk = blockIdx.x; chunk < nchunks; chunk += gridDim.x) {
    const int row0 = chunk * 32;
    __syncthreads();
    for (int i = t; i < 1024; i += 256) {
      const int rr = i >> 5, cc = (i & 31) * 4;
      const int grow = row0 + rr;
      float4 v = make_float4(0.f, 0.f, 0.f, 0.f);
      if (grow < nrows) v = *reinterpret_cast<const float4*>(in + (size_t)grow * HH + cc);
      *reinterpret_cast<float4*>(&rows_s[rr][cc]) = v;
    }
    __syncthreads();

    float acc[4][4] = {};
#pragma unroll 4
    for (int k = 0; k < 128; k += 4) {
      float4 a[4];
#pragma unroll
      for (int r = 0; r < 4; ++r) a[r] = *reinterpret_cast<const float4*>(&rows_s[rowg + r][k]);
#pragma unroll
      for (int kk = 0; kk < 4; ++kk) {
        const float4 wv = *reinterpret_cast<const float4*>(&Ws[k + kk][col4]);
#pragma unroll
        for (int r = 0; r < 4; ++r) {
          const float av = (&a[r].x)[kk];
          acc[r][0] = fmaf(av, wv.x, acc[r][0]);
          acc[r][1] = fmaf(av, wv.y, acc[r][1]);
          acc[r][2] = fmaf(av, wv.z, acc[r][2]);
          acc[r][3] = fmaf(av, wv.w, acc[r][3]);
        }
      }
    }

#pragma unroll
    for (int r = 0; r < 4; ++r) {
      const int grow = row0 + rowg + r;
      if (grow < nrows) {
        float4 o;
        o.x = acc[r][0] + b4.x;
        o.y = acc[r][1] + b4.y;
        o.z = acc[r][2] + b4.z;
        o.w = acc[r][3] + b4.w;
        if (RELU) {
          o.x = fmaxf(o.x, 0.f); o.y = fmaxf(o.y, 0.f);
          o.z = fmaxf(o.z, 0.f); o.w = fmaxf(o.w, 0.f);
        }
        *reinterpret_cast<float4*>(out + (size_t)grow * HH + col4) = o;
      }
    }
  }
}

__global__ __launch_bounds__(256) void col_stats_kernel(const float* __restrict__ h,
                                                        float* __restrict__ stats, int nrows) {
  __shared__ float ssum[256], ssq[256];
  const int t = threadIdx.x;
  const int col = t & 127;
  const int half = t >> 7;
  float s = 0.f, q = 0.f;
  for (int r = blockIdx.x * 2 + half; r < nrows; r += gridDim.x * 2) {
    const float v = h[(size_t)r * HH + col];
    s += v;
    q = fmaf(v, v, q);
  }
  ssum[t] = s;
  ssq[t] = q;
  __syncthreads();
  if (t < 128) {
    atomicAdd(&stats[col], ssum[t] + ssum[t + 128]);
    atomicAdd(&stats[128 + col], ssq[t] + ssq[t + 128]);
  }
}

__global__ __launch_bounds__(256) void bn_apply_kernel(float* __restrict__ h,
                                                       const float* __restrict__ stats,
                                                       const float* __restrict__ gamma,
                                                       const float* __restrict__ beta,
                                                       int n4, float invn) {
  __shared__ float scale_s[128], shift_s[128];
  const int t = threadIdx.x;
  if (t < 128) {
    const float mean = stats[t] * invn;
    float var = fmaf(-mean, mean, stats[128 + t] * invn);
    var = fmaxf(var, 0.f);
    const float rs = rsqrtf(var + 1e-5f);
    const float sc = gamma[t] * rs;
    scale_s[t] = sc;
    shift_s[t] = fmaf(-mean, sc, beta[t]);
  }
  __syncthreads();
  float4* h4 = reinterpret_cast<float4*>(h);
  int i = blockIdx.x * blockDim.x + threadIdx.x;
  const int stride = gridDim.x * blockDim.x;
  for (; i < n4; i += stride) {
    const int c = (i & 31) * 4;
    float4 v = h4[i];
    v.x = fmaf(v.x, scale_s[c + 0], shift_s[c + 0]);
    v.y = fmaf(v.y, scale_s[c + 1], shift_s[c + 1]);
    v.z = fmaf(v.z, scale_s[c + 2], shift_s[c + 2]);
    v.w = fmaf(v.w, scale_s[c + 3], shift_s[c + 3]);
    h4[i] = v;
  }
}

// ================= launch =================
extern "C" void kernel_launch(void* const* d_in, const int* in_sizes, int n_in,
                              void* d_out, int out_size, void* d_ws, size_t ws_size,
                              hipStream_t stream) {
  const float* x = (const float*)d_in[0];
  const int* ei = (const int*)d_in[1];
  const float* W1 = (const float*)d_in[2];
  const float* b1 = (const float*)d_in[3];
  const float* W2 = (const float*)d_in[4];
  const float* b2 = (const float*)d_in[5];
  const float* gamma = (const float*)d_in[6];
  const float* beta = (const float*)d_in[7];
  float* out = (float*)d_out;

  auto AL = [](size_t v) { return (v + 255) & ~(size_t)255; };
  const size_t offs_b = AL((size_t)(NN + 1) * 4);
  const size_t srcl_b = AL((size_t)NE * 4);
  const size_t packed_b = AL((size_t)NE * 4);
  const size_t h2d_b = AL((size_t)NEB * NBK * 4);
  const size_t stats_b = AL(256 * 4);
  const size_t x16_b = AL((size_t)NN * HH * 2);
  const size_t wt_b = AL((size_t)128 * 128 * 2);
  const size_t need_A = offs_b + srcl_b + packed_b + h2d_b + stats_b + x16_b + 2 * wt_b;

  // Tier B layout
  const size_t cnt_b = AL((size_t)NN * 4);
  const size_t part_b = AL(64 * 4);
  const size_t need_B = offs_b + cnt_b + part_b + srcl_b + stats_b;

  if (ws_size >= need_A) {
    // ---- Tier A: bucketed CSR + bf16 half-wave 16-deep gather + MFMA MLP ----
    char* p = (char*)d_ws;
    int* offs = (int*)p;       p += offs_b;
    int* srcl = (int*)p;       p += srcl_b;
    u32* packed = (u32*)p;     p += packed_b;
    int* hist2d = (int*)p;     p += h2d_b;
    float* stats = (float*)p;  p += stats_b;
    u16* x16 = (u16*)p;        p += x16_b;   // doubles as h2 after gather
    u16* w1t = (u16*)p;        p += wt_b;
    u16* w2t = (u16*)p;

    prep_kernel<<<3254 + NEB, 256, 0, stream>>>((const float4*)x, (uint4*)x16, W1, w1t,
                                                W2, w2t, stats, ei, hist2d);
    ph3_kernel<<<NEB, 256, 0, stream>>>(ei, hist2d, packed);
    ph4_kernel<<<NBK, 256, 0, stream>>>(hist2d, packed, offs, srcl);

    // h0 (bf16) lives in the first half of d_out
    gather16_kernel<<<2048, 256, 0, stream>>>((const u32*)x16, offs, srcl, (u32*)d_out);

    const int nchunk = NN / 16;  // 3125
    u32* h2 = (u32*)x16;         // x16 is dead after gather
    fused_mlp_kernel<<<512, 256, 0, stream>>>((const u16*)d_out, w1t, b1, w2t, b2,
                                              h2, stats, nchunk);
    bn16_kernel<<<2048, 256, 0, stream>>>(h2, stats, gamma, beta, out, 1.0f / NN);
  } else if (ws_size >= need_B) {
    // ---- Tier B: fp32 CSR gather + VALU GEMM ----
    char* p = (char*)d_ws;
    int* offs = (int*)p;      p += offs_b;
    int* cnt = (int*)p;       p += cnt_b;
    int* partials = (int*)p;  p += part_b;
    int* srcl = (int*)p;      p += srcl_b;
    float* stats = (float*)p;

    zero_int_kernel<<<64, 256, 0, stream>>>(cnt, NN);
    count_kernel<<<(NE + 255) / 256, 256, 0, stream>>>(ei, cnt);
    scan1_kernel<<<NB1, 256, 0, stream>>>(cnt, offs, partials);
    scan2_kernel<<<1, 64, 0, stream>>>(partials, NB1);
    scan3_kernel<<<NB1, 256, 0, stream>>>(offs, cnt, partials);
    fill_kernel<<<(NE + 255) / 256, 256, 0, stream>>>(ei, cnt, srcl);
    gather_kernel<<<1024, 256, 0, stream>>>(x, offs, srcl, out);

    zero_stats_kernel<<<1, 256, 0, stream>>>(stats);
    const int nchunks = (NN + 31) / 32;
    gemm128_kernel<true><<<512, 256, 0, stream>>>(out, W1, b1, out, NN, nchunks);
    gemm128_kernel<false><<<512, 256, 0, stream>>>(out, W2, b2, out, NN, nchunks);
    col_stats_kernel<<<1024, 256, 0, stream>>>(out, stats, NN);
    bn_apply_kernel<<<2048, 256, 0, stream>>>(out, stats, gamma, beta, NN * HH / 4, 1.0f / NN);
  } else {
    // ---- Tier C: atomic scatter (minimal ws) ----
    float* stats = (float*)d_ws;
    copy_x_kernel<<<2048, 256, 0, stream>>>((const float4*)x, (float4*)out, NN * HH / 4);
    const long long sthreads = (long long)NE * 32;
    scatter_kernel<<<(int)((sthreads + 255) / 256), 256, 0, stream>>>(x, ei, out);
    zero_stats_kernel<<<1, 256, 0, stream>>>(stats);
    const int nchunks = (NN + 31) / 32;
    gemm128_kernel<true><<<512, 256, 0, stream>>>(out, W1, b1, out, NN, nchunks);
    gemm128_kernel<false><<<512, 256, 0, stream>>>(out, W2, b2, out, NN, nchunks);
    col_stats_kernel<<<1024, 256, 0, stream>>>(out, stats, NN);
    bn_apply_kernel<<<2048, 256, 0, stream>>>(out, stats, gamma, beta, NN * HH / 4, 1.0f / NN);
  }
}

// Round 13
// 127.477 us; speedup vs baseline: 1.1225x; 1.1225x over previous
//
#include <hip/hip_runtime.h>

typedef unsigned int u32;
typedef unsigned short u16;
typedef __attribute__((ext_vector_type(8))) short short8;
typedef __attribute__((ext_vector_type(4))) float f32x4;

static constexpr int NN = 50000;
static constexpr int NE = 800000;
static constexpr int HH = 128;
static constexpr int NB1 = (NN + 1023) / 1024;   // Tier B scan blocks
static constexpr int NBK = 196;                   // buckets of 256 nodes
static constexpr int EPB = 8192;                  // edges per hist/scatter block
static constexpr int NEB = (NE + EPB - 1) / EPB;  // 98 edge blocks

// ---- bf16 helpers (RNE) ----
__device__ __forceinline__ u32 bf16r(float f) {
  u32 u = __builtin_bit_cast(u32, f);
  return (u + 0x7FFFu + ((u >> 16) & 1u)) >> 16;
}
__device__ __forceinline__ u32 pk2(float lo, float hi) { return bf16r(lo) | (bf16r(hi) << 16); }
__device__ __forceinline__ float bl(u32 p) { return __builtin_bit_cast(float, p << 16); }
__device__ __forceinline__ float bh(u32 p) { return __builtin_bit_cast(float, p & 0xFFFF0000u); }

// ================= prep + ph1 bucket histogram =================
// blocks [0,3125): cvt_x ; [3125,3189): w1t ; [3189,3253): w2t ;
// 3253: zero stats ; [3254, 3254+NEB): per-edge-block bucket histogram
__global__ __launch_bounds__(256) void prep_kernel(const float4* __restrict__ x,
                                                   uint4* __restrict__ x16,
                                                   const float* __restrict__ W1,
                                                   u16* __restrict__ w1t,
                                                   const float* __restrict__ W2,
                                                   u16* __restrict__ w2t,
                                                   float* __restrict__ stats,
                                                   const int* __restrict__ ei,
                                                   int* __restrict__ hist2d) {
  __shared__ int hist[NBK];
  const int b = blockIdx.x, t = threadIdx.x;
  if (b < 3125) {
    const int i = b * 256 + t;  // < 800000 = NN*HH/8
    const float4 a = x[2 * i];
    const float4 c = x[2 * i + 1];
    uint4 o;
    o.x = pk2(a.x, a.y);
    o.y = pk2(a.z, a.w);
    o.z = pk2(c.x, c.y);
    o.w = pk2(c.z, c.w);
    x16[i] = o;
  } else if (b < 3189) {
    const int o = (b - 3125) * 256 + t;  // < 16384
    const int n = o >> 7, k = o & 127;
    w1t[o] = (u16)bf16r(W1[k * 128 + n]);
  } else if (b < 3253) {
    const int o = (b - 3189) * 256 + t;
    const int n = o >> 7, k = o & 127;
    w2t[o] = (u16)bf16r(W2[k * 128 + n]);
  } else if (b == 3253) {
    stats[t] = 0.f;
  } else {
    const int hb = b - 3254;  // [0, NEB)
    for (int i = t; i < NBK; i += 256) hist[i] = 0;
    __syncthreads();
    const int e0 = hb * EPB;
    const int e1 = min(e0 + EPB, NE);
    for (int e = e0 + t; e < e1; e += 256) atomicAdd(&hist[ei[NE + e] >> 8], 1);
    __syncthreads();
    for (int i = t; i < NBK; i += 256) hist2d[hb * NBK + i] = hist[i];
  }
}

// ================= ph2: bucket bases + per-(block,bucket) bases ==============
__global__ __launch_bounds__(256) void ph2_kernel(const int* __restrict__ hist2d,
                                                  int* __restrict__ block_base,
                                                  int* __restrict__ bucket_offs,
                                                  int* __restrict__ offs) {
  __shared__ int tsum[256];
  const int t = threadIdx.x;
  int total = 0;
  if (t < NBK)
    for (int b = 0; b < NEB; ++b) total += hist2d[b * NBK + t];
  tsum[t] = total;
  __syncthreads();
  for (int off = 1; off < 256; off <<= 1) {
    const int add = (t >= off) ? tsum[t - off] : 0;
    __syncthreads();
    tsum[t] += add;
    __syncthreads();
  }
  const int excl = t ? tsum[t - 1] : 0;
  if (t < NBK) {
    bucket_offs[t] = excl;
    int run = excl;
    for (int b = 0; b < NEB; ++b) {
      block_base[b * NBK + t] = run;
      run += hist2d[b * NBK + t];
    }
  }
  if (t == 0) {
    bucket_offs[NBK] = NE;
    offs[NN] = NE;
  }
}

// ================= ph3: scatter edges into bucket-contiguous packed array ====
__global__ __launch_bounds__(256) void ph3_kernel(const int* __restrict__ ei,
                                                  const int* __restrict__ block_base,
                                                  u32* __restrict__ packed) {
  __shared__ int cur[NBK];
  const int b = blockIdx.x, t = threadIdx.x;
  for (int i = t; i < NBK; i += 256) cur[i] = block_base[b * NBK + i];
  __syncthreads();
  const int e0 = b * EPB;
  const int e1 = min(e0 + EPB, NE);
  for (int e = e0 + t; e < e1; e += 256) {
    const int s = ei[e];
    const int d = ei[NE + e];
    const int pos = atomicAdd(&cur[d >> 8], 1);
    packed[pos] = (u32)s | ((u32)(d & 255) << 16);
  }
}

// ================= ph4: per-bucket counting sort -> srcl + offs ==============
__global__ __launch_bounds__(256) void ph4_kernel(const u32* __restrict__ packed,
                                                  const int* __restrict__ bucket_offs,
                                                  int* __restrict__ offs,
                                                  int* __restrict__ srcl) {
  __shared__ int hist[256];
  __shared__ int scn[256];
  const int b = blockIdx.x, t = threadIdx.x;
  const int base = bucket_offs[b];
  const int cnt = bucket_offs[b + 1] - base;
  hist[t] = 0;
  __syncthreads();
  for (int i = t; i < cnt; i += 256) atomicAdd(&hist[packed[base + i] >> 16], 1);
  __syncthreads();
  scn[t] = hist[t];
  __syncthreads();
  for (int off = 1; off < 256; off <<= 1) {
    const int add = (t >= off) ? scn[t - off] : 0;
    __syncthreads();
    scn[t] += add;
    __syncthreads();
  }
  const int excl = t ? scn[t - 1] : 0;
  const int node = b * 256 + t;
  if (node < NN) offs[node] = base + excl;
  __syncthreads();
  hist[t] = excl;  // reuse as cursor
  __syncthreads();
  for (int i = t; i < cnt; i += 256) {
    const u32 p = packed[base + i];
    const int r = atomicAdd(&hist[p >> 16], 1);
    srcl[base + r] = (int)(p & 0xFFFFu);
  }
}

// ================= gather (bf16, half-wave per node, 8-deep MLP) =============
__global__ __launch_bounds__(256) void gather16_kernel(const u32* __restrict__ x16,
                                                       const int* __restrict__ offs,
                                                       const int* __restrict__ srcl,
                                                       u32* __restrict__ h0) {
  const int hw = (blockIdx.x * 256 + threadIdx.x) >> 5;  // half-wave id
  const int l31 = threadIdx.x & 31;
  const int nhw = gridDim.x * 8;
  for (int node = hw; node < NN; node += nhw) {
    const uint2 sv = reinterpret_cast<const uint2*>(x16 + (size_t)node * 64)[l31];
    float a0 = bl(sv.x), a1 = bh(sv.x), a2 = bl(sv.y), a3 = bh(sv.y);
    const int beg = offs[node], end = offs[node + 1];
    int e = beg;
    for (; e + 8 <= end; e += 8) {
      int s[8];
#pragma unroll
      for (int j = 0; j < 8; ++j) s[j] = srcl[e + j];
      uint2 v[8];
#pragma unroll
      for (int j = 0; j < 8; ++j)
        v[j] = reinterpret_cast<const uint2*>(x16 + (size_t)s[j] * 64)[l31];
#pragma unroll
      for (int j = 0; j < 8; ++j) {
        a0 += bl(v[j].x); a1 += bh(v[j].x);
        a2 += bl(v[j].y); a3 += bh(v[j].y);
      }
    }
    for (; e < end; ++e) {
      const uint2 v = reinterpret_cast<const uint2*>(x16 + (size_t)srcl[e] * 64)[l31];
      a0 += bl(v.x); a1 += bh(v.x);
      a2 += bl(v.y); a3 += bh(v.y);
    }
    uint2 o;
    o.x = pk2(a0, a1);
    o.y = pk2(a2, a3);
    reinterpret_cast<uint2*>(h0 + (size_t)node * 64)[l31] = o;
  }
}

// ---------------- fused 2-layer MLP (MFMA) + column stats --------------------
__global__ __launch_bounds__(256) void fused_mlp_kernel(const u16* __restrict__ h0,
                                                        const u16* __restrict__ w1t,
                                                        const float* __restrict__ b1,
                                                        const u16* __restrict__ w2t,
                                                        const float* __restrict__ b2,
                                                        u32* __restrict__ h2,
                                                        float* __restrict__ stats,
                                                        int nchunk) {
  __shared__ __align__(16) u16 hs[16][136];  // padded: 272B row stride
  __shared__ float sstats[256];
  const int t = threadIdx.x;
  const int w = t >> 6;
  const int lane = t & 63;
  const int lhi = lane >> 4, llo = lane & 15;
  sstats[t] = 0.f;

  short8 w1f[2][4], w2f[2][4];
  float4 bs1[2], bs2[2];
#pragma unroll
  for (int c = 0; c < 2; ++c) {
    const int ct = 2 * w + c;
#pragma unroll
    for (int kb = 0; kb < 4; ++kb) {
      w1f[c][kb] = *reinterpret_cast<const short8*>(w1t + (size_t)(16 * ct + llo) * 128 + kb * 32 + lhi * 8);
      w2f[c][kb] = *reinterpret_cast<const short8*>(w2t + (size_t)(16 * ct + llo) * 128 + kb * 32 + lhi * 8);
    }
    bs1[c] = *reinterpret_cast<const float4*>(b1 + ct * 16 + lhi * 4);
    bs2[c] = *reinterpret_cast<const float4*>(b2 + ct * 16 + lhi * 4);
  }
  __syncthreads();  // sstats init visible to all

  for (int ch = blockIdx.x; ch < nchunk; ch += gridDim.x) {
    const int row0 = ch * 16;

    // ---- layer 1: A from global ----
    const u16* arow = h0 + (size_t)(row0 + llo) * 128;
    short8 afr[4];
#pragma unroll
    for (int kb = 0; kb < 4; ++kb)
      afr[kb] = *reinterpret_cast<const short8*>(arow + kb * 32 + lhi * 8);

    f32x4 acc0 = {0.f, 0.f, 0.f, 0.f};
    f32x4 acc1 = {0.f, 0.f, 0.f, 0.f};
#pragma unroll
    for (int kb = 0; kb < 4; ++kb) {
      acc0 = __builtin_amdgcn_mfma_f32_16x16x32_bf16(w1f[0][kb], afr[kb], acc0, 0, 0, 0);
      acc1 = __builtin_amdgcn_mfma_f32_16x16x32_bf16(w1f[1][kb], afr[kb], acc1, 0, 0, 0);
    }

    // ---- ReLU + pack to LDS ----
#pragma unroll
    for (int c = 0; c < 2; ++c) {
      const int ct = 2 * w + c;
      const f32x4 a = c ? acc1 : acc0;
      const float4 bb = c ? bs1[1] : bs1[0];
      const float v0 = fmaxf(a[0] + bb.x, 0.f);
      const float v1 = fmaxf(a[1] + bb.y, 0.f);
      const float v2 = fmaxf(a[2] + bb.z, 0.f);
      const float v3 = fmaxf(a[3] + bb.w, 0.f);
      u32* dst = reinterpret_cast<u32*>(&hs[llo][ct * 16 + lhi * 4]);
      dst[0] = pk2(v0, v1);
      dst[1] = pk2(v2, v3);
    }
    __syncthreads();

    // ---- layer 2: A from LDS ----
    short8 af2[4];
#pragma unroll
    for (int kb = 0; kb < 4; ++kb)
      af2[kb] = *reinterpret_cast<const short8*>(&hs[llo][kb * 32 + lhi * 8]);

    f32x4 dcc0 = {0.f, 0.f, 0.f, 0.f};
    f32x4 dcc1 = {0.f, 0.f, 0.f, 0.f};
#pragma unroll
    for (int kb = 0; kb < 4; ++kb) {
      dcc0 = __builtin_amdgcn_mfma_f32_16x16x32_bf16(w2f[0][kb], af2[kb], dcc0, 0, 0, 0);
      dcc1 = __builtin_amdgcn_mfma_f32_16x16x32_bf16(w2f[1][kb], af2[kb], dcc1, 0, 0, 0);
    }
    __syncthreads();  // protect hs before next chunk's writes

    // ---- epilogue: bias, bf16 store, fused column stats ----
#pragma unroll
    for (int c = 0; c < 2; ++c) {
      const int ct = 2 * w + c;
      const f32x4 a = c ? dcc1 : dcc0;
      const float4 bb = c ? bs2[1] : bs2[0];
      float v0 = a[0] + bb.x;
      float v1 = a[1] + bb.y;
      float v2 = a[2] + bb.z;
      float v3 = a[3] + bb.w;
      u32* op = h2 + (size_t)(row0 + llo) * 64 + ct * 8 + lhi * 2;
      op[0] = pk2(v0, v1);
      op[1] = pk2(v2, v3);
      float q0 = v0 * v0, q1 = v1 * v1, q2 = v2 * v2, q3 = v3 * v3;
#pragma unroll
      for (int m = 1; m < 16; m <<= 1) {
        v0 += __shfl_xor(v0, m, 64); v1 += __shfl_xor(v1, m, 64);
        v2 += __shfl_xor(v2, m, 64); v3 += __shfl_xor(v3, m, 64);
        q0 += __shfl_xor(q0, m, 64); q1 += __shfl_xor(q1, m, 64);
        q2 += __shfl_xor(q2, m, 64); q3 += __shfl_xor(q3, m, 64);
      }
      if (llo == 0) {
        const int cb = ct * 16 + lhi * 4;
        atomicAdd(&sstats[cb + 0], v0); atomicAdd(&sstats[cb + 1], v1);
        atomicAdd(&sstats[cb + 2], v2); atomicAdd(&sstats[cb + 3], v3);
        atomicAdd(&sstats[128 + cb + 0], q0); atomicAdd(&sstats[128 + cb + 1], q1);
        atomicAdd(&sstats[128 + cb + 2], q2); atomicAdd(&sstats[128 + cb + 3], q3);
      }
    }
  }
  __syncthreads();
  atomicAdd(&stats[t], sstats[t]);
}

// ---------------- batchnorm: h2 bf16 -> out fp32 ----------------
__global__ __launch_bounds__(256) void bn16_kernel(const u32* __restrict__ h2,
                                                   const float* __restrict__ stats,
                                                   const float* __restrict__ gamma,
                                                   const float* __restrict__ beta,
                                                   float* __restrict__ out, float invn) {
  __shared__ float scale_s[128], shift_s[128];
  const int t = threadIdx.x;
  if (t < 128) {
    const float mean = stats[t] * invn;
    float var = fmaf(-mean, mean, stats[128 + t] * invn);
    var = fmaxf(var, 0.f);
    const float rs = rsqrtf(var + 1e-5f);
    const float sc = gamma[t] * rs;
    scale_s[t] = sc;
    shift_s[t] = fmaf(-mean, sc, beta[t]);
  }
  __syncthreads();
  int i = blockIdx.x * 256 + t;
  const int stride = gridDim.x * 256;
  for (; i < NN * 64; i += stride) {
    const int c = (i & 63) * 2;
    const u32 p = h2[i];
    float2 o;
    o.x = fmaf(bl(p), scale_s[c + 0], shift_s[c + 0]);
    o.y = fmaf(bh(p), scale_s[c + 1], shift_s[c + 1]);
    *reinterpret_cast<float2*>(out + 2 * (size_t)i) = o;
  }
}

// ================= Tier B/C fallback kernels (fp32) =================
__global__ void zero_stats_kernel(float* __restrict__ stats) { stats[threadIdx.x] = 0.f; }

__global__ __launch_bounds__(256) void zero_int_kernel(int* __restrict__ p, int n) {
  int i = blockIdx.x * blockDim.x + threadIdx.x;
  const int stride = gridDim.x * blockDim.x;
  for (; i < n; i += stride) p[i] = 0;
}

__global__ __launch_bounds__(256) void count_kernel(const int* __restrict__ ei,
                                                    int* __restrict__ cnt) {
  const int e = blockIdx.x * blockDim.x + threadIdx.x;
  if (e < NE) atomicAdd(&cnt[ei[NE + e]], 1);
}

__global__ __launch_bounds__(256) void scan1_kernel(const int* __restrict__ cnt,
                                                    int* __restrict__ offs,
                                                    int* __restrict__ partials) {
  __shared__ int tsum[256];
  const int b = blockIdx.x, t = threadIdx.x;
  const int base = b * 1024 + t * 4;
  int v[4];
  int s = 0;
#pragma unroll
  for (int j = 0; j < 4; ++j) {
    const int idx = base + j;
    v[j] = (idx < NN) ? cnt[idx] : 0;
    s += v[j];
  }
  tsum[t] = s;
  __syncthreads();
#pragma unroll
  for (int off = 1; off < 256; off <<= 1) {
    const int add = (t >= off) ? tsum[t - off] : 0;
    __syncthreads();
    tsum[t] += add;
    __syncthreads();
  }
  int excl = (t ? tsum[t - 1] : 0);
#pragma unroll
  for (int j = 0; j < 4; ++j) {
    const int idx = base + j;
    if (idx < NN) offs[idx] = excl;
    excl += v[j];
  }
  if (t == 255) partials[b] = tsum[255];
}

__global__ void scan2_kernel(int* __restrict__ partials, int nb) {
  const int t = threadIdx.x;
  int v = (t < nb) ? partials[t] : 0;
#pragma unroll
  for (int off = 1; off < 64; off <<= 1) {
    const int n = __shfl_up(v, off, 64);
    if (t >= off) v += n;
  }
  int excl = __shfl_up(v, 1, 64);
  if (t == 0) excl = 0;
  if (t < nb) partials[t] = excl;
}

__global__ __launch_bounds__(256) void scan3_kernel(int* __restrict__ offs,
                                                    int* __restrict__ cursor,
                                                    const int* __restrict__ partials) {
  const int b = blockIdx.x;
  const int add = partials[b];
#pragma unroll
  for (int j = 0; j < 4; ++j) {
    const int idx = b * 1024 + threadIdx.x + j * 256;
    if (idx < NN) {
      const int o = offs[idx] + add;
      offs[idx] = o;
      cursor[idx] = o;
    }
  }
  if (b == 0 && threadIdx.x == 0) offs[NN] = NE;
}

__global__ __launch_bounds__(256) void fill_kernel(const int* __restrict__ ei,
                                                   int* __restrict__ cursor,
                                                   int* __restrict__ srcl) {
  const int e = blockIdx.x * blockDim.x + threadIdx.x;
  if (e >= NE) return;
  const int s = ei[e];
  const int d = ei[NE + e];
  const int pos = atomicAdd(&cursor[d], 1);
  srcl[pos] = s;
}

__global__ __launch_bounds__(256) void gather_kernel(const float* __restrict__ x,
                                                     const int* __restrict__ offs,
                                                     const int* __restrict__ srcl,
                                                     float* __restrict__ out) {
  const int wave = (blockIdx.x * 256 + threadIdx.x) >> 6;
  const int lane = threadIdx.x & 63;
  const int nwaves = gridDim.x * 4;
  for (int node = wave; node < NN; node += nwaves) {
    float2 acc = *reinterpret_cast<const float2*>(x + (size_t)node * HH + lane * 2);
    const int beg = offs[node], end = offs[node + 1];
    for (int e = beg; e < end; ++e) {
      const int s = srcl[e];
      const float2 v = *reinterpret_cast<const float2*>(x + (size_t)s * HH + lane * 2);
      acc.x += v.x;
      acc.y += v.y;
    }
    *reinterpret_cast<float2*>(out + (size_t)node * HH + lane * 2) = acc;
  }
}

__global__ __launch_bounds__(256) void copy_x_kernel(const float4* __restrict__ x,
                                                     float4* __restrict__ h, int n4) {
  int i = blockIdx.x * blockDim.x + threadIdx.x;
  const int stride = gridDim.x * blockDim.x;
  for (; i < n4; i += stride) h[i] = x[i];
}

__global__ __launch_bounds__(256) void scatter_kernel(const float* __restrict__ x,
                                                      const int* __restrict__ ei,
                                                      float* __restrict__ h) {
  const long long tid = (long long)blockIdx.x * blockDim.x + threadIdx.x;
  const int e = (int)(tid >> 5);
  if (e >= NE) return;
  const int c = (int)(tid & 31);
  const int s = ei[e];
  const int d = ei[NE + e];
  const float4 v = *reinterpret_cast<const float4*>(x + (size_t)s * HH + c * 4);
  float* dp = h + (size_t)d * HH + c * 4;
  atomicAdd(dp + 0, v.x);
  atomicAdd(dp + 1, v.y);
  atomicAdd(dp + 2, v.z);
  atomicAdd(dp + 3, v.w);
}

template <bool RELU>
__global__ __launch_bounds__(256, 2) void gemm128_kernel(const float* in,
                                                         const float* __restrict__ W,
                                                         const float* __restrict__ bias,
                                                         float* out,
                                                         int nrows, int nchunks) {
  __shared__ float Ws[128][128];
  __shared__ float rows_s[32][128];
  const int t = threadIdx.x;
  for (int i = t; i < 128 * 128 / 4; i += 256) {
    reinterpret_cast<float4*>(&Ws[0][0])[i] = reinterpret_cast<const float4*>(W)[i];
  }
  const int col4 = (t & 31) * 4;
  const int rowg = (t >> 5) * 4;
  const float4 b4 = *reinterpret_cast<const float4*>(bias + col4);

  for (int chunk = blockIdx.x; chunk < nchunks; chunk += gridDim.x) {
    const int row0 = chunk * 32;
    __syncthreads();
    for (int i = t; i < 1024; i += 256) {
      const int rr = i >> 5, cc = (i & 31) * 4;
      const int grow = row0 + rr;
      float4 v = make_float4(0.f, 0.f, 0.f, 0.f);
      if (grow < nrows) v = *reinterpret_cast<const float4*>(in + (size_t)grow * HH + cc);
      *reinterpret_cast<float4*>(&rows_s[rr][cc]) = v;
    }
    __syncthreads();

    float acc[4][4] = {};
#pragma unroll 4
    for (int k = 0; k < 128; k += 4) {
      float4 a[4];
#pragma unroll
      for (int r = 0; r < 4; ++r) a[r] = *reinterpret_cast<const float4*>(&rows_s[rowg + r][k]);
#pragma unroll
      for (int kk = 0; kk < 4; ++kk) {
        const float4 wv = *reinterpret_cast<const float4*>(&Ws[k + kk][col4]);
#pragma unroll
        for (int r = 0; r < 4; ++r) {
          const float av = (&a[r].x)[kk];
          acc[r][0] = fmaf(av, wv.x, acc[r][0]);
          acc[r][1] = fmaf(av, wv.y, acc[r][1]);
          acc[r][2] = fmaf(av, wv.z, acc[r][2]);
          acc[r][3] = fmaf(av, wv.w, acc[r][3]);
        }
      }
    }

#pragma unroll
    for (int r = 0; r < 4; ++r) {
      const int grow = row0 + rowg + r;
      if (grow < nrows) {
        float4 o;
        o.x = acc[r][0] + b4.x;
        o.y = acc[r][1] + b4.y;
        o.z = acc[r][2] + b4.z;
        o.w = acc[r][3] + b4.w;
        if (RELU) {
          o.x = fmaxf(o.x, 0.f); o.y = fmaxf(o.y, 0.f);
          o.z = fmaxf(o.z, 0.f); o.w = fmaxf(o.w, 0.f);
        }
        *reinterpret_cast<float4*>(out + (size_t)grow * HH + col4) = o;
      }
    }
  }
}

__global__ __launch_bounds__(256) void col_stats_kernel(const float* __restrict__ h,
                                                        float* __restrict__ stats, int nrows) {
  __shared__ float ssum[256], ssq[256];
  const int t = threadIdx.x;
  const int col = t & 127;
  const int half = t >> 7;
  float s = 0.f, q = 0.f;
  for (int r = blockIdx.x * 2 + half; r < nrows; r += gridDim.x * 2) {
    const float v = h[(size_t)r * HH + col];
    s += v;
    q = fmaf(v, v, q);
  }
  ssum[t] = s;
  ssq[t] = q;
  __syncthreads();
  if (t < 128) {
    atomicAdd(&stats[col], ssum[t] + ssum[t + 128]);
    atomicAdd(&stats[128 + col], ssq[t] + ssq[t + 128]);
  }
}

__global__ __launch_bounds__(256) void bn_apply_kernel(float* __restrict__ h,
                                                       const float* __restrict__ stats,
                                                       const float* __restrict__ gamma,
                                                       const float* __restrict__ beta,
                                                       int n4, float invn) {
  __shared__ float scale_s[128], shift_s[128];
  const int t = threadIdx.x;
  if (t < 128) {
    const float mean = stats[t] * invn;
    float var = fmaf(-mean, mean, stats[128 + t] * invn);
    var = fmaxf(var, 0.f);
    const float rs = rsqrtf(var + 1e-5f);
    const float sc = gamma[t] * rs;
    scale_s[t] = sc;
    shift_s[t] = fmaf(-mean, sc, beta[t]);
  }
  __syncthreads();
  float4* h4 = reinterpret_cast<float4*>(h);
  int i = blockIdx.x * blockDim.x + threadIdx.x;
  const int stride = gridDim.x * blockDim.x;
  for (; i < n4; i += stride) {
    const int c = (i & 31) * 4;
    float4 v = h4[i];
    v.x = fmaf(v.x, scale_s[c + 0], shift_s[c + 0]);
    v.y = fmaf(v.y, scale_s[c + 1], shift_s[c + 1]);
    v.z = fmaf(v.z, scale_s[c + 2], shift_s[c + 2]);
    v.w = fmaf(v.w, scale_s[c + 3], shift_s[c + 3]);
    h4[i] = v;
  }
}

// ================= launch =================
extern "C" void kernel_launch(void* const* d_in, const int* in_sizes, int n_in,
                              void* d_out, int out_size, void* d_ws, size_t ws_size,
                              hipStream_t stream) {
  const float* x = (const float*)d_in[0];
  const int* ei = (const int*)d_in[1];
  const float* W1 = (const float*)d_in[2];
  const float* b1 = (const float*)d_in[3];
  const float* W2 = (const float*)d_in[4];
  const float* b2 = (const float*)d_in[5];
  const float* gamma = (const float*)d_in[6];
  const float* beta = (const float*)d_in[7];
  float* out = (float*)d_out;

  auto AL = [](size_t v) { return (v + 255) & ~(size_t)255; };
  const size_t offs_b = AL((size_t)(NN + 1) * 4);
  const size_t srcl_b = AL((size_t)NE * 4);
  const size_t packed_b = AL((size_t)NE * 4);
  const size_t h2d_b = AL((size_t)NEB * NBK * 4);
  const size_t bb_b = AL((size_t)NEB * NBK * 4);
  const size_t boffs_b = AL((size_t)(NBK + 1) * 4);
  const size_t stats_b = AL(256 * 4);
  const size_t x16_b = AL((size_t)NN * HH * 2);
  const size_t wt_b = AL((size_t)128 * 128 * 2);
  const size_t need_A = offs_b + srcl_b + packed_b + h2d_b + bb_b + boffs_b + stats_b +
                        x16_b + 2 * wt_b;

  // Tier B layout
  const size_t cnt_b = AL((size_t)NN * 4);
  const size_t part_b = AL(64 * 4);
  const size_t need_B = offs_b + cnt_b + part_b + srcl_b + stats_b;

  if (ws_size >= need_A) {
    // ---- Tier A (round-6 best config): bucketed CSR + bf16 half-wave 8-deep
    //      gather + fused MFMA MLP + bf16 BN ----
    char* p = (char*)d_ws;
    int* offs = (int*)p;       p += offs_b;
    int* srcl = (int*)p;       p += srcl_b;
    u32* packed = (u32*)p;     p += packed_b;
    int* hist2d = (int*)p;     p += h2d_b;
    int* block_base = (int*)p; p += bb_b;
    int* boffs = (int*)p;      p += boffs_b;
    float* stats = (float*)p;  p += stats_b;
    u16* x16 = (u16*)p;        p += x16_b;   // doubles as h2 after gather
    u16* w1t = (u16*)p;        p += wt_b;
    u16* w2t = (u16*)p;

    prep_kernel<<<3254 + NEB, 256, 0, stream>>>((const float4*)x, (uint4*)x16, W1, w1t,
                                                W2, w2t, stats, ei, hist2d);
    ph2_kernel<<<1, 256, 0, stream>>>(hist2d, block_base, boffs, offs);
    ph3_kernel<<<NEB, 256, 0, stream>>>(ei, block_base, packed);
    ph4_kernel<<<NBK, 256, 0, stream>>>(packed, boffs, offs, srcl);

    // h0 (bf16) lives in the first half of d_out
    gather16_kernel<<<2048, 256, 0, stream>>>((const u32*)x16, offs, srcl, (u32*)d_out);

    const int nchunk = NN / 16;  // 3125
    u32* h2 = (u32*)x16;         // x16 is dead after gather
    fused_mlp_kernel<<<512, 256, 0, stream>>>((const u16*)d_out, w1t, b1, w2t, b2,
                                              h2, stats, nchunk);
    bn16_kernel<<<2048, 256, 0, stream>>>(h2, stats, gamma, beta, out, 1.0f / NN);
  } else if (ws_size >= need_B) {
    // ---- Tier B: fp32 CSR gather + VALU GEMM ----
    char* p = (char*)d_ws;
    int* offs = (int*)p;      p += offs_b;
    int* cnt = (int*)p;       p += cnt_b;
    int* partials = (int*)p;  p += part_b;
    int* srcl = (int*)p;      p += srcl_b;
    float* stats = (float*)p;

    zero_int_kernel<<<64, 256, 0, stream>>>(cnt, NN);
    count_kernel<<<(NE + 255) / 256, 256, 0, stream>>>(ei, cnt);
    scan1_kernel<<<NB1, 256, 0, stream>>>(cnt, offs, partials);
    scan2_kernel<<<1, 64, 0, stream>>>(partials, NB1);
    scan3_kernel<<<NB1, 256, 0, stream>>>(offs, cnt, partials);
    fill_kernel<<<(NE + 255) / 256, 256, 0, stream>>>(ei, cnt, srcl);
    gather_kernel<<<1024, 256, 0, stream>>>(x, offs, srcl, out);

    zero_stats_kernel<<<1, 256, 0, stream>>>(stats);
    const int nchunks = (NN + 31) / 32;
    gemm128_kernel<true><<<512, 256, 0, stream>>>(out, W1, b1, out, NN, nchunks);
    gemm128_kernel<false><<<512, 256, 0, stream>>>(out, W2, b2, out, NN, nchunks);
    col_stats_kernel<<<1024, 256, 0, stream>>>(out, stats, NN);
    bn_apply_kernel<<<2048, 256, 0, stream>>>(out, stats, gamma, beta, NN * HH / 4, 1.0f / NN);
  } else {
    // ---- Tier C: atomic scatter (minimal ws) ----
    float* stats = (float*)d_ws;
    copy_x_kernel<<<2048, 256, 0, stream>>>((const float4*)x, (float4*)out, NN * HH / 4);
    const long long sthreads = (long long)NE * 32;
    scatter_kernel<<<(int)((sthreads + 255) / 256), 256, 0, stream>>>(x, ei, out);
    zero_stats_kernel<<<1, 256, 0, stream>>>(stats);
    const int nchunks = (NN + 31) / 32;
    gemm128_kernel<true><<<512, 256, 0, stream>>>(out, W1, b1, out, NN, nchunks);
    gemm128_kernel<false><<<512, 256, 0, stream>>>(out, W2, b2, out, NN, nchunks);
    col_stats_kernel<<<1024, 256, 0, stream>>>(out, stats, NN);
    bn_apply_kernel<<<2048, 256, 0, stream>>>(out, stats, gamma, beta, NN * HH / 4, 1.0f / NN);
  }
}